// Round 1
// baseline (739.506 us; speedup 1.0000x reference)
//
#include <hip/hip_runtime.h>
#include <math.h>

// B=4, T=2048, D=2048, K=8 -> S=9 sources per (b,t).
// Outputs concatenated in d_out: routed_hidden [B*T*D], weights [B*T*S], entropy [B*T].
constexpr int Bdim = 4;
constexpr int Tdim = 2048;
constexpr int Ddim = 2048;
constexpr int Kdim = 8;
constexpr int Sdim = Kdim + 1;      // 9
constexpr float EPSF = 1e-8f;

// One workgroup per (b,t). 256 threads x 8 floats = 2048 = D.
// Each thread keeps all 9 source fragments (72 floats) in registers so global
// data is read exactly once (single-pass: stats -> softmax -> combine).
__global__ __launch_bounds__(256, 2) void bar_routed_kernel(
    const float* __restrict__ embedding,   // [B*T*D]
    const float* __restrict__ blocks,      // [K*B*T*D]
    const float* __restrict__ query,       // [D]
    const float* __restrict__ key_weight,  // [D]
    float* __restrict__ routed,            // [B*T*D]
    float* __restrict__ weights_out,       // [B*T*S]
    float* __restrict__ entropy_out)       // [B*T]
{
    const int bt  = blockIdx.x;           // 0 .. B*T-1
    const int tid = threadIdx.x;          // 0 .. 255
    const int d0  = tid * 8;

    // q[d] * key_weight[d] for this thread's 8 dims
    const float4 qa = *reinterpret_cast<const float4*>(query + d0);
    const float4 qb = *reinterpret_cast<const float4*>(query + d0 + 4);
    const float4 wa = *reinterpret_cast<const float4*>(key_weight + d0);
    const float4 wb = *reinterpret_cast<const float4*>(key_weight + d0 + 4);
    const float qw[8] = {qa.x * wa.x, qa.y * wa.y, qa.z * wa.z, qa.w * wa.w,
                         qb.x * wb.x, qb.y * wb.y, qb.z * wb.z, qb.w * wb.w};

    float v[Sdim][8];
    float ss[Sdim];   // sum of squares per source (partial)
    float dt[Sdim];   // dot(src, q*w) per source (partial)

    #pragma unroll
    for (int s = 0; s < Sdim; ++s) {
        const float* src = (s == 0)
            ? embedding + (size_t)bt * Ddim + d0
            : blocks + ((size_t)(s - 1) * (Bdim * Tdim) + (size_t)bt) * (size_t)Ddim + d0;
        const float4 a = *reinterpret_cast<const float4*>(src);
        const float4 b = *reinterpret_cast<const float4*>(src + 4);
        v[s][0] = a.x; v[s][1] = a.y; v[s][2] = a.z; v[s][3] = a.w;
        v[s][4] = b.x; v[s][5] = b.y; v[s][6] = b.z; v[s][7] = b.w;
        float s2 = 0.0f, dd = 0.0f;
        #pragma unroll
        for (int j = 0; j < 8; ++j) {
            s2 = fmaf(v[s][j], v[s][j], s2);
            dd = fmaf(v[s][j], qw[j], dd);
        }
        ss[s] = s2;
        dt[s] = dd;
    }

    // Wave-64 butterfly: every lane ends with the wave total.
    #pragma unroll
    for (int s = 0; s < Sdim; ++s) {
        #pragma unroll
        for (int off = 32; off >= 1; off >>= 1) {
            ss[s] += __shfl_xor(ss[s], off, 64);
            dt[s] += __shfl_xor(dt[s], off, 64);
        }
    }

    // Cross-wave (4 waves) via LDS.
    __shared__ float red_ss[4][Sdim];
    __shared__ float red_dt[4][Sdim];
    const int wave = tid >> 6;
    const int lane = tid & 63;
    if (lane == 0) {
        #pragma unroll
        for (int s = 0; s < Sdim; ++s) {
            red_ss[wave][s] = ss[s];
            red_dt[wave][s] = dt[s];
        }
    }
    __syncthreads();

    // Every thread computes the 9-way softmax redundantly (cheap scalars).
    float w[Sdim];
    float lmax = -1e30f;
    #pragma unroll
    for (int s = 0; s < Sdim; ++s) {
        const float tss = red_ss[0][s] + red_ss[1][s] + red_ss[2][s] + red_ss[3][s];
        const float tdt = red_dt[0][s] + red_dt[1][s] + red_dt[2][s] + red_dt[3][s];
        // logits = dot / sqrt(mean(src^2) + eps); rms divides keys, weight*query folded into dt.
        const float logit = tdt * rsqrtf(tss * (1.0f / (float)Ddim) + EPSF);
        w[s] = logit;
        lmax = fmaxf(lmax, logit);
    }
    float esum = 0.0f;
    #pragma unroll
    for (int s = 0; s < Sdim; ++s) {
        w[s] = expf(w[s] - lmax);
        esum += w[s];
    }
    const float inv = 1.0f / esum;
    float ent = 0.0f;
    #pragma unroll
    for (int s = 0; s < Sdim; ++s) {
        w[s] *= inv;
        const float cw = fmaxf(w[s], 1e-12f);
        ent -= cw * logf(cw);
    }

    // Weighted combine of raw sources from registers; coalesced float4 stores.
    float o[8];
    #pragma unroll
    for (int j = 0; j < 8; ++j) {
        float acc = 0.0f;
        #pragma unroll
        for (int s = 0; s < Sdim; ++s) acc = fmaf(w[s], v[s][j], acc);
        o[j] = acc;
    }
    float* outp = routed + (size_t)bt * Ddim + d0;
    *reinterpret_cast<float4*>(outp)     = make_float4(o[0], o[1], o[2], o[3]);
    *reinterpret_cast<float4*>(outp + 4) = make_float4(o[4], o[5], o[6], o[7]);

    if (tid < Sdim) weights_out[(size_t)bt * Sdim + tid] = w[tid];
    if (tid == 0)  entropy_out[bt] = ent;
}

extern "C" void kernel_launch(void* const* d_in, const int* in_sizes, int n_in,
                              void* d_out, int out_size, void* d_ws, size_t ws_size,
                              hipStream_t stream) {
    const float* embedding  = (const float*)d_in[0];
    const float* blocks     = (const float*)d_in[1];
    const float* query      = (const float*)d_in[2];
    const float* key_weight = (const float*)d_in[3];

    float* routed      = (float*)d_out;
    float* weights_out = routed + (size_t)Bdim * Tdim * Ddim;
    float* entropy_out = weights_out + (size_t)Bdim * Tdim * Sdim;

    dim3 grid(Bdim * Tdim);
    dim3 block(256);
    bar_routed_kernel<<<grid, block, 0, stream>>>(
        embedding, blocks, query, key_weight, routed, weights_out, entropy_out);
}